// Round 2
// baseline (159.619 us; speedup 1.0000x reference)
//
#include <hip/hip_runtime.h>

// Problem constants (fixed by reference setup_inputs)
#define N_PRE 8192
#define N_CUR 16384
#define KNN   8

// Workspace layout (bytes):
//   [0,   128K) : c2p64 u64[N_CUR]    packed (key<<32 | pre_idx), atomicMin-merged
//   [128K,256K) : pre4 float4[N_PRE]  (-2px, -2py, -2pz, |p|^2)
//   [256K,512K) : cur4 float4[N_CUR]  ( cx,   cy,   cz,  |c|^2)
//
// Comparator trick: for a fixed query q, ordering by true sqdist equals
// ordering by (|cand|^2 - 2 cand.q)  -> 3 FMA per candidate.
// d can be NEGATIVE -> monotone float->u32 key map; packed (key,idx) u64
// min == (min d, then min idx) — identical tie-break everywhere.
//
// R2 changes (theory: B is LDS-pipe-throughput-bound, A is serial-chain-bound):
//  A: pre dimension sliced 4x across blocks (32 inner iters/wave instead of
//     128), partial argmins merged via atomicMin on packed u64 (commutative
//     -> deterministic). 16384 waves, one barrier per block.
//  B: 2 pre/wave (halves ds_read service time, the dominant cost) and the
//     top-8 list is REPLICATED in all lanes' registers: each pop event needs
//     only ONE bpermute (broadcast d; candidate idx = tile+s+src is computed,
//     not shuffled; t8 threshold is lane-local). Insert = 8 cmp + cndmask
//     cascade on the idle VALU pipe.

#define MAPPED_INF 0xFF800000u  // monotone key of +inf (empty-slot sentinel)

__device__ __forceinline__ unsigned key_of(float d) {
    unsigned b = __float_as_uint(d);
    return b ^ (0x80000000u | (unsigned)((int)b >> 31));
}
__device__ __forceinline__ float float_of_key(unsigned k) {
    unsigned b = (k & 0x80000000u) ? (k ^ 0x80000000u) : ~k;
    return __uint_as_float(b);
}
__device__ __forceinline__ unsigned shfl_u32(unsigned x, int src) {
    return (unsigned)__shfl((int)x, src);
}

// Sorted ascending 8-slot insert, all compile-time register indices.
// Precondition: kd < k[7]. Strict < keeps equal-key elements in scan
// (ascending-index) order — same tie-break as the old shfl_up insert.
__device__ __forceinline__ void insert8(unsigned (&k)[8], unsigned (&id)[8],
                                        unsigned kd, unsigned kj) {
    bool m[8];
#pragma unroll
    for (int t = 0; t < 8; ++t) m[t] = kd < k[t];
#pragma unroll
    for (int t = 7; t >= 1; --t) {
        k[t]  = m[t - 1] ? k[t - 1]  : (m[t] ? kd : k[t]);
        id[t] = m[t - 1] ? id[t - 1] : (m[t] ? kj : id[t]);
    }
    k[0]  = m[0] ? kd : k[0];
    id[0] = m[0] ? kj : id[0];
}

// ---------- prep: pack comparator-form coords + init c2p64 ----------
__global__ __launch_bounds__(256) void prep_kernel(
        const float* __restrict__ pre, const float* __restrict__ cur,
        float4* __restrict__ pre4, float4* __restrict__ cur4,
        unsigned long long* __restrict__ c2p64) {
    int i = blockIdx.x * 256 + threadIdx.x;
    if (i < N_CUR) {
        float x = cur[i], y = cur[N_CUR + i], z = cur[2 * N_CUR + i];
        cur4[i] = make_float4(x, y, z, fmaf(x, x, fmaf(y, y, z * z)));
        c2p64[i] = 0xFFFFFFFFFFFFFFFFull;   // > any real packed (key,idx)
    }
    if (i < N_PRE) {
        float x = pre[i], y = pre[N_PRE + i], z = pre[2 * N_PRE + i];
        pre4[i] = make_float4(-2.f * x, -2.f * y, -2.f * z,
                              fmaf(x, x, fmaf(y, y, z * z)));
    }
}

// ---------- Kernel A: cur2pre argmin (pre-sliced + atomicMin merge) ----------
// Block = 16 waves; each block stages ONE 2048-pre slice (32 KB) and its
// waves each own 4 cur points. Wave does 32 inner iterations, butterfly-
// reduces 4 packed (key,idx) values, lane 0 atomicMin's them into c2p64.
#define TILE_A   2048
#define SLICES_A (N_PRE / TILE_A)   // 4

__global__ __launch_bounds__(1024) void cur2pre_kernel(
        const float4* __restrict__ pre4, const float4* __restrict__ cur4,
        unsigned long long* __restrict__ c2p64) {
    __shared__ float4 sp[TILE_A];
    const int tid   = threadIdx.x;
    const int lane  = tid & 63;
    const int w     = tid >> 6;
    const int slice = blockIdx.x & (SLICES_A - 1);
    const int cg    = blockIdx.x >> 2;          // cur group (64 cur / block)
    const int j0    = cg * 64 + w * 4;          // this wave's 4 cur points
    const int sbase = slice * TILE_A;

    const float4 c0 = cur4[j0 + 0];
    const float4 c1 = cur4[j0 + 1];
    const float4 c2 = cur4[j0 + 2];
    const float4 c3 = cur4[j0 + 3];

    for (int k = tid; k < TILE_A; k += 1024) sp[k] = pre4[sbase + k];
    __syncthreads();

    const float INF = __int_as_float(0x7F800000);
    float b0 = INF, b1 = INF, b2 = INF, b3 = INF;
    int   i0 = 0,   i1 = 0,   i2 = 0,   i3 = 0;

#pragma unroll 4
    for (int s = 0; s < TILE_A; s += 64) {
        float4 q = sp[s + lane];
        int idx = sbase + s + lane;
        float d0 = fmaf(q.x, c0.x, fmaf(q.y, c0.y, fmaf(q.z, c0.z, q.w)));
        float d1 = fmaf(q.x, c1.x, fmaf(q.y, c1.y, fmaf(q.z, c1.z, q.w)));
        float d2 = fmaf(q.x, c2.x, fmaf(q.y, c2.y, fmaf(q.z, c2.z, q.w)));
        float d3 = fmaf(q.x, c3.x, fmaf(q.y, c3.y, fmaf(q.z, c3.z, q.w)));
        if (d0 < b0) { b0 = d0; i0 = idx; }
        if (d1 < b1) { b1 = d1; i1 = idx; }
        if (d2 < b2) { b2 = d2; i2 = idx; }
        if (d3 < b3) { b3 = d3; i3 = idx; }
    }

    // 4 independent butterflies, interleaved for ILP
    unsigned long long v0 = (((unsigned long long)key_of(b0)) << 32) | (unsigned)i0;
    unsigned long long v1 = (((unsigned long long)key_of(b1)) << 32) | (unsigned)i1;
    unsigned long long v2 = (((unsigned long long)key_of(b2)) << 32) | (unsigned)i2;
    unsigned long long v3 = (((unsigned long long)key_of(b3)) << 32) | (unsigned)i3;
#pragma unroll
    for (int off = 32; off > 0; off >>= 1) {
        unsigned long long o0 = __shfl_xor(v0, off);
        unsigned long long o1 = __shfl_xor(v1, off);
        unsigned long long o2 = __shfl_xor(v2, off);
        unsigned long long o3 = __shfl_xor(v3, off);
        v0 = (o0 < v0) ? o0 : v0;
        v1 = (o1 < v1) ? o1 : v1;
        v2 = (o2 < v2) ? o2 : v2;
        v3 = (o3 < v3) ? o3 : v3;
    }
    if (lane == 0) {
        atomicMin(c2p64 + j0 + 0, v0);
        atomicMin(c2p64 + j0 + 1, v1);
        atomicMin(c2p64 + j0 + 2, v2);
        atomicMin(c2p64 + j0 + 3, v3);
    }
}

// ---------- Kernel B: per-pre top-8 + masked mean ----------
// Wave handles P=2 pre points; 8 waves/block (512 thr) share one LDS cur
// tile. Fast path per candidate per pre: 3 FMA + 1 float cmp (ballot).
// Top-8 kept REPLICATED in every lane's registers: pop = 1 bpermute only.
#define TILE_B 2048

__global__ __launch_bounds__(512) void knn_finalize_kernel(
        const float4* __restrict__ pre4, const float4* __restrict__ cur4,
        const float* __restrict__ ups,
        const unsigned long long* __restrict__ c2p64,
        float* __restrict__ out) {
    __shared__ float4 sc[TILE_B];
    const int tid  = threadIdx.x;
    const int lane = tid & 63;
    const int w    = tid >> 6;
    const int i0   = blockIdx.x * 16 + w * 2;
    const int i1   = i0 + 1;

    const float4 p0 = pre4[i0];   // (-2p, |p|^2)
    const float4 p1 = pre4[i1];

    unsigned k0_[8], id0_[8], k1_[8], id1_[8];
#pragma unroll
    for (int t = 0; t < 8; ++t) {
        k0_[t] = MAPPED_INF; id0_[t] = 0u;
        k1_[t] = MAPPED_INF; id1_[t] = 0u;
    }
    float t80 = __int_as_float(0x7F800000);
    float t81 = t80;

    for (int tile = 0; tile < N_CUR; tile += TILE_B) {
        __syncthreads();
        for (int k = tid; k < TILE_B; k += 512) sc[k] = cur4[tile + k];
        __syncthreads();

#pragma unroll 4
        for (int s = 0; s < TILE_B; s += 64) {
            float4 c = sc[s + lane];
            float d0 = fmaf(p0.x, c.x, fmaf(p0.y, c.y, fmaf(p0.z, c.z, c.w)));
            float d1 = fmaf(p1.x, c.x, fmaf(p1.y, c.y, fmaf(p1.z, c.z, c.w)));
            const int jbase = tile + s;

            unsigned long long m0 = __ballot(d0 < t80);
            while (m0) {
                int src = __ffsll((unsigned long long)m0) - 1;
                float fd = __uint_as_float(shfl_u32(__float_as_uint(d0), src));
                unsigned kd = key_of(fd);
                unsigned kj = (unsigned)(jbase + src);
                insert8(k0_, id0_, kd, kj);
                t80 = float_of_key(k0_[7]);
                m0 = (m0 & (m0 - 1)) & __ballot(d0 < t80);
            }

            unsigned long long m1 = __ballot(d1 < t81);
            while (m1) {
                int src = __ffsll((unsigned long long)m1) - 1;
                float fd = __uint_as_float(shfl_u32(__float_as_uint(d1), src));
                unsigned kd = key_of(fd);
                unsigned kj = (unsigned)(jbase + src);
                insert8(k1_, id1_, kd, kj);
                t81 = float_of_key(k1_[7]);
                m1 = (m1 & (m1 - 1)) & __ballot(d1 < t81);
            }
        }
    }

    // finalize: lanes 0..7 -> i0's top-8 (ascending), lanes 8..15 -> i1's.
    // Lists are replicated; pick slot (lane&7) with compile-time indices.
    unsigned j = 0;
#pragma unroll
    for (int t = 0; t < 8; ++t) {
        unsigned cand = (lane < 8) ? id0_[t] : id1_[t];
        j = ((lane & 7) == t) ? cand : j;
    }

    float contrib = 0.f;
    if (lane < 16) {
        float4 c = cur4[j];
        float px = -0.5f * ((lane < 8) ? p0.x : p1.x);
        float py = -0.5f * ((lane < 8) ? p0.y : p1.y);
        float pz = -0.5f * ((lane < 8) ? p0.z : p1.z);
        float dx = c.x - px, dy = c.y - py, dz = c.z - pz;
        float dsq = fmaf(dx, dx, fmaf(dy, dy, dz * dz));
        unsigned owner = (unsigned)(c2p64[j] & 0xFFFFFFFFull);
        unsigned iexp  = (lane < 8) ? (unsigned)i0 : (unsigned)i1;
        contrib = (owner == iexp) ? sqrtf(dsq) : 0.f;
    }
    contrib += __shfl_xor(contrib, 1);
    contrib += __shfl_xor(contrib, 2);
    contrib += __shfl_xor(contrib, 4);
    if (lane == 0) out[i0] = contrib / ups[i0];
    if (lane == 8) out[i1] = contrib / ups[i1];
}

// ---------- launch ----------
extern "C" void kernel_launch(void* const* d_in, const int* in_sizes, int n_in,
                              void* d_out, int out_size, void* d_ws, size_t ws_size,
                              hipStream_t stream) {
    const float* pre = (const float*)d_in[0];   // (1,3,8192)
    const float* cur = (const float*)d_in[1];   // (1,3,16384)
    const float* ups = (const float*)d_in[2];   // (1,8192)
    float* out = (float*)d_out;                 // (1,8192)

    char* ws = (char*)d_ws;
    unsigned long long* c2p64 = (unsigned long long*)ws;      // 128 KB
    float4* pre4 = (float4*)(ws + 131072);                    // 128 KB
    float4* cur4 = (float4*)(ws + 131072 + 131072);           // 256 KB

    prep_kernel<<<N_CUR / 256, 256, 0, stream>>>(pre, cur, pre4, cur4, c2p64);

    // A: 256 cur-groups x 4 pre-slices = 1024 blocks x 16 waves
    cur2pre_kernel<<<(N_CUR / 64) * SLICES_A, 1024, 0, stream>>>(pre4, cur4, c2p64);

    // B: 512 blocks x 8 waves, 2 pre per wave
    knn_finalize_kernel<<<N_PRE / 16, 512, 0, stream>>>(pre4, cur4, ups, c2p64, out);
}